// Round 2
// baseline (6096.755 us; speedup 1.0000x reference)
//
#include <hip/hip_runtime.h>

#define B_   64
#define T_   512
#define IN_  512
#define HID_ 1024
#define OUT_ 512

#define BROW 1092        // hs staging row stride (floats): 1024 data + skew pads
#define RED_STRIDE 260   // reduction slice stride (floats), aliases hs
#define HS_FLOATS 8728   // 34.9 KB static LDS

// ---------------------------------------------------------------------------
// K0: transpose W_hh [j][k] -> Wt [k][j] so scan W reads are lane-coalesced.
// ---------------------------------------------------------------------------
__global__ __launch_bounds__(256) void transpose_whh(const float* __restrict__ W,
                                                     float* __restrict__ Wt) {
  __shared__ float tile[32][33];
  const int bx = blockIdx.x * 32;  // k
  const int by = blockIdx.y * 32;  // j
  const int tx = threadIdx.x;
  const int ty = threadIdx.y;
#pragma unroll
  for (int i = 0; i < 32; i += 8)
    tile[ty + i][tx] = W[(size_t)(by + ty + i) * HID_ + bx + tx];
  __syncthreads();
#pragma unroll
  for (int i = 0; i < 32; i += 8)
    Wt[(size_t)(bx + ty + i) * HID_ + by + tx] = tile[tx][ty + i];
}

// ---------------------------------------------------------------------------
// K1/K3: C[M,N] = A[M,K] @ B[N,K]^T + bias[N].  fp32, 128x128 tile, BK=8.
// ---------------------------------------------------------------------------
__global__ __launch_bounds__(256) void gemm_bias(const float* __restrict__ A,
                                                 const float* __restrict__ Bm,
                                                 const float* __restrict__ bias,
                                                 float* __restrict__ C,
                                                 int M, int N, int K) {
  __shared__ float As[8][128];
  __shared__ float Bs[8][128];
  const int bm = blockIdx.y * 128;
  const int bn = blockIdx.x * 128;
  const int tid = threadIdx.x;
  const int tr = (tid / 16) * 8;
  const int tc = (tid % 16) * 8;
  const int lr = tid / 2;
  const int lk = (tid % 2) * 4;

  float acc[8][8];
#pragma unroll
  for (int i = 0; i < 8; i++)
#pragma unroll
    for (int j = 0; j < 8; j++) acc[i][j] = 0.f;

  for (int k0 = 0; k0 < K; k0 += 8) {
    float4 a = *(const float4*)&A[(size_t)(bm + lr) * K + k0 + lk];
    float4 b = *(const float4*)&Bm[(size_t)(bn + lr) * K + k0 + lk];
    As[lk + 0][lr] = a.x; As[lk + 1][lr] = a.y;
    As[lk + 2][lr] = a.z; As[lk + 3][lr] = a.w;
    Bs[lk + 0][lr] = b.x; Bs[lk + 1][lr] = b.y;
    Bs[lk + 2][lr] = b.z; Bs[lk + 3][lr] = b.w;
    __syncthreads();
#pragma unroll
    for (int k = 0; k < 8; k++) {
      float av[8], bv[8];
#pragma unroll
      for (int i = 0; i < 8; i++) av[i] = As[k][tr + i];
#pragma unroll
      for (int j = 0; j < 8; j++) bv[j] = Bs[k][tc + j];
#pragma unroll
      for (int i = 0; i < 8; i++)
#pragma unroll
        for (int j = 0; j < 8; j++) acc[i][j] += av[i] * bv[j];
    }
    __syncthreads();
  }

#pragma unroll
  for (int i = 0; i < 8; i++) {
#pragma unroll
    for (int j = 0; j < 8; j += 4) {
      float4 o;
      o.x = acc[i][j + 0] + bias[bn + tc + j + 0];
      o.y = acc[i][j + 1] + bias[bn + tc + j + 1];
      o.z = acc[i][j + 2] + bias[bn + tc + j + 2];
      o.w = acc[i][j + 3] + bias[bn + tc + j + 3];
      *(float4*)&C[(size_t)(bm + tr + i) * N + bn + tc + j] = o;
    }
  }
}

// ---------------------------------------------------------------------------
// K2: persistent scan, plain launch. 256 blocks = 32 j-slices x 8 groups.
// NO fences, NO fetch_add: flag-per-block barrier through L3.  All cross-
// block data moves via agent-scope atomics = L3 coherence point;
// __syncthreads' vmcnt(0) drain before the flag store gives "flag visible
// => h visible".  W lives in VGPRs (loop-invariant, preloaded once):
// zero per-step W traffic (was 32 MB/step x 512 = 16.4 GB of L2 reads).
// 1 block/CU (1 wave/SIMD) so the VGPR budget up to 256 is free;
// __launch_bounds__(256,1) lifts the allocator cap.
// Thread map: q=tid&7 -> 4-j quad, ks=tid>>3 (0..31) -> 32-k slice.
// Per thread: 32k x 4j x 8b = 1024 FMA.
// ---------------------------------------------------------------------------
__global__ __launch_bounds__(256, 1) void rnn_scan6(const float* __restrict__ Wt,
                                                    float* __restrict__ hall,
                                                    int* __restrict__ flags) {
  __shared__ float hs[HS_FLOATS];  // staging [8][BROW]; red alias [32][RED_STRIDE]

  const int bid = blockIdx.x;
  const int jg = bid & 31;
  const int bg = bid >> 5;
  const int j0 = jg * 32;
  const int b0 = bg * 8;
  const int tid = threadIdx.x;
  const int q  = tid & 7;
  const int ks = tid >> 3;

  const float* wbase = Wt + (size_t)(ks * 32) * HID_ + j0 + q * 4;
  const float* hsbase = hs + ks * 32 + (ks >> 1) * 4;

  // --- preload the thread's loop-invariant W slice: rows ks*32..+31, cols q*4..+3
  float4 w[32];
#pragma unroll
  for (int kk = 0; kk < 32; ++kk)
    w[kk] = *(const float4*)(wbase + (size_t)kk * HID_);

  for (int t = 0; t < T_; ++t) {
    // --- wait for step t-1 (parallel flag poll, wave 0 only)
    if (t > 0 && tid < 64) {
      const int* f = flags + (((bg << 9) + (t - 1)) << 5) + (tid & 31);
      while (true) {
        int v = __hip_atomic_load(f, __ATOMIC_RELAXED, __HIP_MEMORY_SCOPE_AGENT);
        if (__ballot(v != 0) == ~0ull) break;
      }
      __asm__ __volatile__("" ::: "memory");
    }
    __syncthreads();

    // --- prefetch xp (own j-slice of row t; block-private)
    float4 xpv = make_float4(0.f, 0.f, 0.f, 0.f);
    float* xpaddr = nullptr;
    if (tid < 64) {
      xpaddr = &hall[((size_t)(b0 + (tid >> 3)) * T_ + t) * HID_ + j0 + (tid & 7) * 4];
      xpv = *(const float4*)xpaddr;
    }

    float4 acc[8];
#pragma unroll
    for (int bi = 0; bi < 8; ++bi) acc[bi] = make_float4(0.f, 0.f, 0.f, 0.f);

    if (t > 0) {
      const int tp = t - 1;
      // --- stage h(t-1): 8 rows x 1024 floats via coherent u64 loads
#pragma unroll
      for (int s = 0; s < 16; ++s) {
        const int F2 = tid + 256 * s;
        const int b  = F2 >> 9;
        const int k2 = F2 & 511;
        const unsigned long long* src = (const unsigned long long*)
            &hall[((size_t)(b0 + b) * T_ + tp) * HID_ + 2 * k2];
        unsigned long long v =
            __hip_atomic_load(src, __ATOMIC_RELAXED, __HIP_MEMORY_SCOPE_AGENT);
        *(unsigned long long*)&hs[b * BROW + 2 * k2 + (k2 >> 5) * 4] = v;
      }
      __syncthreads();

      // --- compute: 8 groups of 4 k; per g: 4k x 4j x 8b = 128 FMA, W from VGPR
#pragma unroll
      for (int g = 0; g < 8; ++g) {
        const int kk = g * 4;
#pragma unroll
        for (int bi = 0; bi < 8; ++bi) {
          const float4 hv = *(const float4*)(hsbase + bi * BROW + kk);
          acc[bi].x += hv.x * w[kk].x + hv.y * w[kk + 1].x + hv.z * w[kk + 2].x + hv.w * w[kk + 3].x;
          acc[bi].y += hv.x * w[kk].y + hv.y * w[kk + 1].y + hv.z * w[kk + 2].y + hv.w * w[kk + 3].y;
          acc[bi].z += hv.x * w[kk].z + hv.y * w[kk + 1].z + hv.z * w[kk + 2].z + hv.w * w[kk + 3].z;
          acc[bi].w += hv.x * w[kk].w + hv.y * w[kk + 1].w + hv.z * w[kk + 2].w + hv.w * w[kk + 3].w;
        }
      }
      __syncthreads();  // all hs reads done before red overwrites
    }

    // --- write partial sums to red (aliases hs)
#pragma unroll
    for (int bi = 0; bi < 8; ++bi)
      *(float4*)&hs[ks * RED_STRIDE + bi * 32 + q * 4] = acc[bi];
    __syncthreads();

    // --- reduce 32 k-slices, tanh, publish h(t) to the coherence point
    if (tid < 64) {
      const int off = (tid >> 3) * 32 + (tid & 7) * 4;
      float4 sum = make_float4(0.f, 0.f, 0.f, 0.f);
#pragma unroll
      for (int kss = 0; kss < 32; ++kss) {
        const float4 r = *(const float4*)&hs[kss * RED_STRIDE + off];
        sum.x += r.x; sum.y += r.y; sum.z += r.z; sum.w += r.w;
      }
      union { float f[4]; unsigned long long u[2]; } pk;
      pk.f[0] = tanhf(sum.x + xpv.x);
      pk.f[1] = tanhf(sum.y + xpv.y);
      pk.f[2] = tanhf(sum.z + xpv.z);
      pk.f[3] = tanhf(sum.w + xpv.w);
      unsigned long long* dst = (unsigned long long*)xpaddr;
      __hip_atomic_store(dst + 0, pk.u[0], __ATOMIC_RELAXED, __HIP_MEMORY_SCOPE_AGENT);
      __hip_atomic_store(dst + 1, pk.u[1], __ATOMIC_RELAXED, __HIP_MEMORY_SCOPE_AGENT);
    }
    __syncthreads();  // vmcnt(0): h stores acked at L3 before flag store

    // --- arrival: one agent store to this block's own flag slot
    if (tid == 0)
      __hip_atomic_store(flags + (((bg << 9) + t) << 5) + jg, 1,
                         __ATOMIC_RELAXED, __HIP_MEMORY_SCOPE_AGENT);
  }
}

// ---------------------------------------------------------------------------
extern "C" void kernel_launch(void* const* d_in, const int* in_sizes, int n_in,
                              void* d_out, int out_size, void* d_ws, size_t ws_size,
                              hipStream_t stream) {
  (void)in_sizes; (void)n_in; (void)out_size; (void)ws_size;
  const float* input = (const float*)d_in[0];
  const float* W_ih  = (const float*)d_in[1];
  const float* W_hh  = (const float*)d_in[2];
  const float* bias  = (const float*)d_in[3];
  const float* W_out = (const float*)d_in[4];
  const float* b_out = (const float*)d_in[5];
  float* out = (float*)d_out;

  float* Wt   = (float*)d_ws;                  // 4 MiB
  float* hall = Wt + (size_t)HID_ * HID_;      // 128 MiB (x_proj, then h)
  // Flags live in the head of d_out: zeroed here, overwritten by K3 at the end.
  int* flags = (int*)d_out;                    // 8 groups x 512 t x 32 slots = 512 KiB

  hipMemsetAsync(flags, 0, (size_t)8 * T_ * 32 * sizeof(int), stream);

  transpose_whh<<<dim3(32, 32), dim3(32, 8), 0, stream>>>(W_hh, Wt);

  gemm_bias<<<dim3(HID_ / 128, (B_ * T_) / 128), 256, 0, stream>>>(
      input, W_ih, bias, hall, B_ * T_, HID_, IN_);

  rnn_scan6<<<dim3(256), dim3(256), 0, stream>>>(Wt, hall, flags);

  gemm_bias<<<dim3(OUT_ / 128, (B_ * T_) / 128), 256, 0, stream>>>(
      hall, W_out, b_out, out, B_ * T_, OUT_, HID_);
}

// Round 4
// 5457.528 us; speedup vs baseline: 1.1171x; 1.1171x over previous
//
#include <hip/hip_runtime.h>

#define B_   64
#define T_   512
#define IN_  512
#define HID_ 1024
#define OUT_ 512

#define BROW 1092        // hs staging row stride (floats): 1024 data + skew pads
#define RED_STRIDE 260   // reduction slice stride (floats), aliases hs
#define HS_FLOATS 8728   // 34.9 KB static LDS

// ---------------------------------------------------------------------------
// K0: transpose W_hh [j][k] -> Wt [k][j] so scan W reads are lane-coalesced.
// ---------------------------------------------------------------------------
__global__ __launch_bounds__(256) void transpose_whh(const float* __restrict__ W,
                                                     float* __restrict__ Wt) {
  __shared__ float tile[32][33];
  const int bx = blockIdx.x * 32;  // k
  const int by = blockIdx.y * 32;  // j
  const int tx = threadIdx.x;
  const int ty = threadIdx.y;
#pragma unroll
  for (int i = 0; i < 32; i += 8)
    tile[ty + i][tx] = W[(size_t)(by + ty + i) * HID_ + bx + tx];
  __syncthreads();
#pragma unroll
  for (int i = 0; i < 32; i += 8)
    Wt[(size_t)(bx + ty + i) * HID_ + by + tx] = tile[tx][ty + i];
}

// ---------------------------------------------------------------------------
// K1/K3: C[M,N] = A[M,K] @ B[N,K]^T + bias[N].  fp32, 128x128 tile, BK=8.
// ---------------------------------------------------------------------------
__global__ __launch_bounds__(256) void gemm_bias(const float* __restrict__ A,
                                                 const float* __restrict__ Bm,
                                                 const float* __restrict__ bias,
                                                 float* __restrict__ C,
                                                 int M, int N, int K) {
  __shared__ float As[8][128];
  __shared__ float Bs[8][128];
  const int bm = blockIdx.y * 128;
  const int bn = blockIdx.x * 128;
  const int tid = threadIdx.x;
  const int tr = (tid / 16) * 8;
  const int tc = (tid % 16) * 8;
  const int lr = tid / 2;
  const int lk = (tid % 2) * 4;

  float acc[8][8];
#pragma unroll
  for (int i = 0; i < 8; i++)
#pragma unroll
    for (int j = 0; j < 8; j++) acc[i][j] = 0.f;

  for (int k0 = 0; k0 < K; k0 += 8) {
    float4 a = *(const float4*)&A[(size_t)(bm + lr) * K + k0 + lk];
    float4 b = *(const float4*)&Bm[(size_t)(bn + lr) * K + k0 + lk];
    As[lk + 0][lr] = a.x; As[lk + 1][lr] = a.y;
    As[lk + 2][lr] = a.z; As[lk + 3][lr] = a.w;
    Bs[lk + 0][lr] = b.x; Bs[lk + 1][lr] = b.y;
    Bs[lk + 2][lr] = b.z; Bs[lk + 3][lr] = b.w;
    __syncthreads();
#pragma unroll
    for (int k = 0; k < 8; k++) {
      float av[8], bv[8];
#pragma unroll
      for (int i = 0; i < 8; i++) av[i] = As[k][tr + i];
#pragma unroll
      for (int j = 0; j < 8; j++) bv[j] = Bs[k][tc + j];
#pragma unroll
      for (int i = 0; i < 8; i++)
#pragma unroll
        for (int j = 0; j < 8; j++) acc[i][j] += av[i] * bv[j];
    }
    __syncthreads();
  }

#pragma unroll
  for (int i = 0; i < 8; i++) {
#pragma unroll
    for (int j = 0; j < 8; j += 4) {
      float4 o;
      o.x = acc[i][j + 0] + bias[bn + tc + j + 0];
      o.y = acc[i][j + 1] + bias[bn + tc + j + 1];
      o.z = acc[i][j + 2] + bias[bn + tc + j + 2];
      o.w = acc[i][j + 3] + bias[bn + tc + j + 3];
      *(float4*)&C[(size_t)(bm + tr + i) * N + bn + tc + j] = o;
    }
  }
}

// ---------------------------------------------------------------------------
// K2: persistent scan. 256 blocks = 32 j-slices x 8 groups, 1 block/CU.
// W in VGPRs (loop-invariant).  Pipelined handoff:
//  - wave 1 polls flags(t-1) at loop-top, CONCURRENT with wave 0 finishing
//    step t-1's reduce -> publish -> wave-local s_waitcnt(0) -> flag store.
//  - poll is WAVE-UNIFORM: all 64 lanes run one loop; own-slot lanes use
//    a select (v = own ? 1 : load) so __ballot runs with all 64 lanes
//    active.  (R2 version branched -> ballot over partial masks -> hang.)
//  - own-slice h short-circuits through LDS: wave 0 writes pk into its
//    staging slot; the staging loop skips own columns.
// Invariant: flag(t) visible => h(t) stores acked at L3 (wave-0
// s_waitcnt(0) before flag store; all publish stores issued by wave 0).
// ---------------------------------------------------------------------------
__global__ __launch_bounds__(256, 1) void rnn_scan8(const float* __restrict__ Wt,
                                                    float* __restrict__ hall,
                                                    int* __restrict__ flags) {
  __shared__ float hs[HS_FLOATS];  // staging [8][BROW]; red alias [32][RED_STRIDE]

  const int bid = blockIdx.x;
  const int jg = bid & 31;
  const int bg = bid >> 5;
  const int j0 = jg * 32;
  const int b0 = bg * 8;
  const int tid = threadIdx.x;
  const int q  = tid & 7;
  const int ks = tid >> 3;

  const float* wbase = Wt + (size_t)(ks * 32) * HID_ + j0 + q * 4;
  const float* hsbase = hs + ks * 32 + (ks >> 1) * 4;
  const int ownskew = (j0 >> 6) << 2;  // staging skew for own-col window

  // --- preload the thread's loop-invariant W slice: rows ks*32..+31, cols q*4..+3
  float4 w[32];
#pragma unroll
  for (int kk = 0; kk < 32; ++kk)
    w[kk] = *(const float4*)(wbase + (size_t)kk * HID_);

  for (int t = 0; t < T_; ++t) {
    // --- wave 1: uniform poll of flags(t-1); own slot short-circuits via
    //     select (no divergent branch around __ballot).
    if (t > 0 && tid >= 64 && tid < 128) {
      const int slot = tid & 31;
      const bool own = (slot == jg);
      const int* f = flags + (((bg << 9) + (t - 1)) << 5) + slot;
      while (true) {
        int v = own ? 1
                    : __hip_atomic_load(f, __ATOMIC_RELAXED, __HIP_MEMORY_SCOPE_AGENT);
        if (__ballot(v != 0) == ~0ull) break;
      }
      __asm__ __volatile__("" ::: "memory");
    }
    __syncthreads();  // [2]: meet of {poll done (w1), publish acked (w0)}

    // --- prefetch xp (own j-slice of row t; block-private)
    float4 xpv = make_float4(0.f, 0.f, 0.f, 0.f);
    float* xpaddr = nullptr;
    if (tid < 64) {
      xpaddr = &hall[((size_t)(b0 + (tid >> 3)) * T_ + t) * HID_ + j0 + (tid & 7) * 4];
      xpv = *(const float4*)xpaddr;
    }

    float4 acc[8];
#pragma unroll
    for (int bi = 0; bi < 8; ++bi) acc[bi] = make_float4(0.f, 0.f, 0.f, 0.f);

    if (t > 0) {
      const int tp = t - 1;
      // --- stage h(t-1): skip own 32-col window (seeded via LDS by wave 0)
#pragma unroll
      for (int s = 0; s < 16; ++s) {
        const int F2 = tid + 256 * s;
        const int b  = F2 >> 9;
        const int k2 = F2 & 511;
        if ((k2 >> 4) != jg) {
          const unsigned long long* src = (const unsigned long long*)
              &hall[((size_t)(b0 + b) * T_ + tp) * HID_ + 2 * k2];
          unsigned long long v =
              __hip_atomic_load(src, __ATOMIC_RELAXED, __HIP_MEMORY_SCOPE_AGENT);
          *(unsigned long long*)&hs[b * BROW + 2 * k2 + (k2 >> 5) * 4] = v;
        }
      }
      __syncthreads();

      // --- compute: 8 groups of 4 k; per g: 4k x 4j x 8b = 128 FMA, W from VGPR
#pragma unroll
      for (int g = 0; g < 8; ++g) {
        const int kk = g * 4;
#pragma unroll
        for (int bi = 0; bi < 8; ++bi) {
          const float4 hv = *(const float4*)(hsbase + bi * BROW + kk);
          acc[bi].x += hv.x * w[kk].x + hv.y * w[kk + 1].x + hv.z * w[kk + 2].x + hv.w * w[kk + 3].x;
          acc[bi].y += hv.x * w[kk].y + hv.y * w[kk + 1].y + hv.z * w[kk + 2].y + hv.w * w[kk + 3].y;
          acc[bi].z += hv.x * w[kk].z + hv.y * w[kk + 1].z + hv.z * w[kk + 2].z + hv.w * w[kk + 3].z;
          acc[bi].w += hv.x * w[kk].w + hv.y * w[kk + 1].w + hv.z * w[kk + 2].w + hv.w * w[kk + 3].w;
        }
      }
      __syncthreads();  // all hs reads done before red overwrites
    }

    // --- write partial sums to red (aliases hs)
#pragma unroll
    for (int bi = 0; bi < 8; ++bi)
      *(float4*)&hs[ks * RED_STRIDE + bi * 32 + q * 4] = acc[bi];
    __syncthreads();  // [9]: red complete; waves 1-3 run ahead to next poll

    // --- wave 0: reduce, tanh, seed own LDS slot, publish, ack, flag
    if (tid < 64) {
      const int off = (tid >> 3) * 32 + (tid & 7) * 4;
      float4 sum = make_float4(0.f, 0.f, 0.f, 0.f);
#pragma unroll
      for (int kss = 0; kss < 32; ++kss) {
        const float4 r = *(const float4*)&hs[kss * RED_STRIDE + off];
        sum.x += r.x; sum.y += r.y; sum.z += r.z; sum.w += r.w;
      }
      union { float f[4]; unsigned long long u[2]; } pk;
      pk.f[0] = tanhf(sum.x + xpv.x);
      pk.f[1] = tanhf(sum.y + xpv.y);
      pk.f[2] = tanhf(sum.z + xpv.z);
      pk.f[3] = tanhf(sum.w + xpv.w);

      // own-slice -> staging slot (LDS). Program order after all red reads
      // of this wave; in-order LDS per wave makes this safe.
      const int ob = tid >> 3;
      const int ojq = tid & 7;
      *(float4*)&hs[ob * BROW + j0 + ojq * 4 + ownskew] = *(const float4*)pk.f;

      // publish to hall (other blocks + final GEMM)
      unsigned long long* dst = (unsigned long long*)xpaddr;
      __hip_atomic_store(dst + 0, pk.u[0], __ATOMIC_RELAXED, __HIP_MEMORY_SCOPE_AGENT);
      __hip_atomic_store(dst + 1, pk.u[1], __ATOMIC_RELAXED, __HIP_MEMORY_SCOPE_AGENT);

      // wave-local drain: all 64 lanes' publish stores acked at L3.
      __asm__ __volatile__("" ::: "memory");
      __builtin_amdgcn_s_waitcnt(0);

      if (tid == 0)
        __hip_atomic_store(flags + (((bg << 9) + t) << 5) + jg, 1,
                           __ATOMIC_RELAXED, __HIP_MEMORY_SCOPE_AGENT);
    }
    // no block-wide barrier here: next iteration's [2] provides it; the
    // LDS own-slot write is drained by [2]'s lgkmcnt(0), and staging of
    // step t+1 cannot start before [2].
  }
}

// ---------------------------------------------------------------------------
extern "C" void kernel_launch(void* const* d_in, const int* in_sizes, int n_in,
                              void* d_out, int out_size, void* d_ws, size_t ws_size,
                              hipStream_t stream) {
  (void)in_sizes; (void)n_in; (void)out_size; (void)ws_size;
  const float* input = (const float*)d_in[0];
  const float* W_ih  = (const float*)d_in[1];
  const float* W_hh  = (const float*)d_in[2];
  const float* bias  = (const float*)d_in[3];
  const float* W_out = (const float*)d_in[4];
  const float* b_out = (const float*)d_in[5];
  float* out = (float*)d_out;

  float* Wt   = (float*)d_ws;                  // 4 MiB
  float* hall = Wt + (size_t)HID_ * HID_;      // 128 MiB (x_proj, then h)
  // Flags live in the head of d_out: zeroed here, overwritten by K3 at the end.
  int* flags = (int*)d_out;                    // 8 groups x 512 t x 32 slots = 512 KiB

  hipMemsetAsync(flags, 0, (size_t)8 * T_ * 32 * sizeof(int), stream);

  transpose_whh<<<dim3(32, 32), dim3(32, 8), 0, stream>>>(W_hh, Wt);

  gemm_bias<<<dim3(HID_ / 128, (B_ * T_) / 128), 256, 0, stream>>>(
      input, W_ih, bias, hall, B_ * T_, HID_, IN_);

  rnn_scan8<<<dim3(256), dim3(256), 0, stream>>>(Wt, hall, flags);

  gemm_bias<<<dim3(OUT_ / 128, (B_ * T_) / 128), 256, 0, stream>>>(
      hall, W_out, b_out, out, B_ * T_, OUT_, HID_);
}

// Round 6
// 4157.676 us; speedup vs baseline: 1.4664x; 1.3126x over previous
//
#include <hip/hip_runtime.h>

#define B_   64
#define T_   512
#define IN_  512
#define HID_ 1024
#define OUT_ 512

#define BROW 1092        // hs staging row stride (floats): 1024 data + skew pads
#define RED_STRIDE 260   // reduction slice stride (floats)
#define REDSZ (32 * RED_STRIDE)

typedef unsigned long long u64;

// ---------------------------------------------------------------------------
// K0: transpose W_hh [j][k] -> Wt [k][j] so scan W reads are lane-coalesced.
// ---------------------------------------------------------------------------
__global__ __launch_bounds__(256) void transpose_whh(const float* __restrict__ W,
                                                     float* __restrict__ Wt) {
  __shared__ float tile[32][33];
  const int bx = blockIdx.x * 32;  // k
  const int by = blockIdx.y * 32;  // j
  const int tx = threadIdx.x;
  const int ty = threadIdx.y;
#pragma unroll
  for (int i = 0; i < 32; i += 8)
    tile[ty + i][tx] = W[(size_t)(by + ty + i) * HID_ + bx + tx];
  __syncthreads();
#pragma unroll
  for (int i = 0; i < 32; i += 8)
    Wt[(size_t)(bx + ty + i) * HID_ + by + tx] = tile[tx][ty + i];
}

// ---------------------------------------------------------------------------
// K1/K3: C[M,N] = A[M,K] @ B[N,K]^T + bias[N].  fp32, 128x128 tile, BK=8.
// ---------------------------------------------------------------------------
__global__ __launch_bounds__(256) void gemm_bias(const float* __restrict__ A,
                                                 const float* __restrict__ Bm,
                                                 const float* __restrict__ bias,
                                                 float* __restrict__ C,
                                                 int M, int N, int K) {
  __shared__ float As[8][128];
  __shared__ float Bs[8][128];
  const int bm = blockIdx.y * 128;
  const int bn = blockIdx.x * 128;
  const int tid = threadIdx.x;
  const int tr = (tid / 16) * 8;
  const int tc = (tid % 16) * 8;
  const int lr = tid / 2;
  const int lk = (tid % 2) * 4;

  float acc[8][8];
#pragma unroll
  for (int i = 0; i < 8; i++)
#pragma unroll
    for (int j = 0; j < 8; j++) acc[i][j] = 0.f;

  for (int k0 = 0; k0 < K; k0 += 8) {
    float4 a = *(const float4*)&A[(size_t)(bm + lr) * K + k0 + lk];
    float4 b = *(const float4*)&Bm[(size_t)(bn + lr) * K + k0 + lk];
    As[lk + 0][lr] = a.x; As[lk + 1][lr] = a.y;
    As[lk + 2][lr] = a.z; As[lk + 3][lr] = a.w;
    Bs[lk + 0][lr] = b.x; Bs[lk + 1][lr] = b.y;
    Bs[lk + 2][lr] = b.z; Bs[lk + 3][lr] = b.w;
    __syncthreads();
#pragma unroll
    for (int k = 0; k < 8; k++) {
      float av[8], bv[8];
#pragma unroll
      for (int i = 0; i < 8; i++) av[i] = As[k][tr + i];
#pragma unroll
      for (int j = 0; j < 8; j++) bv[j] = Bs[k][tc + j];
#pragma unroll
      for (int i = 0; i < 8; i++)
#pragma unroll
        for (int j = 0; j < 8; j++) acc[i][j] += av[i] * bv[j];
    }
    __syncthreads();
  }

#pragma unroll
  for (int i = 0; i < 8; i++) {
#pragma unroll
    for (int j = 0; j < 8; j += 4) {
      float4 o;
      o.x = acc[i][j + 0] + bias[bn + tc + j + 0];
      o.y = acc[i][j + 1] + bias[bn + tc + j + 1];
      o.z = acc[i][j + 2] + bias[bn + tc + j + 2];
      o.w = acc[i][j + 3] + bias[bn + tc + j + 3];
      *(float4*)&C[(size_t)(bm + tr + i) * N + bn + tc + j] = o;
    }
  }
}

// ---------------------------------------------------------------------------
// K2: persistent scan, epoch-tagged data handoff.  256 blocks = 32 jg x 8 bg,
// 1 block/CU, W in VGPRs.
//   - h exchanged via hx[2][B][HID] of u64 {hi32: step tag, lo32: h bits}.
//     Producer fire-and-forgets tagged stores (NO s_waitcnt ack, NO flags).
//     Consumer staging loads ARE the poll: retry until tag == t-1.  u64
//     atomics are single-copy atomic; tags disambiguate parity-slot reuse.
//   - per-wave staging: wave w consumes exactly k in [256w,256w+256), stages
//     its own LDS columns, needs NO barrier before compute, and waits on
//     only its 8 producer blocks.
//   - red ping-pong (parity t&1) -> ONE barrier/step (red-write -> reduce).
//     WAR: wave w's red[p] write at t+2 follows barrier(t+1), which wave0
//     reaches only after its reduce(t) reads of red[p].
//   - h also stored PLAIN to hall row t (final GEMM input; kernel-end flush).
// Deadlock-freedom: producers publish before any shared barrier; chain
// grounds at t=0 (no staging).  2-deep ping-pong cannot overwrite-race:
// every block's step t+1 needs h(t) from ALL 32 peers, so no block gets
// 2 steps ahead of any peer.
// ---------------------------------------------------------------------------
__global__ __launch_bounds__(256, 1) void rnn_scan9(const float* __restrict__ Wt,
                                                    float* __restrict__ hall,
                                                    u64* __restrict__ hx) {
  __shared__ float hs[8 * BROW];   // staging, per-wave disjoint column ranges
  __shared__ float red[2 * REDSZ]; // ping-pong partial sums

  const int bid = blockIdx.x;
  const int jg = bid & 31;
  const int bg = bid >> 5;
  const int j0 = jg * 32;
  const int b0 = bg * 8;
  const int tid = threadIdx.x;
  const int q  = tid & 7;
  const int ks = tid >> 3;
  const int wv = tid >> 6;   // wave id 0..3; wave w stages k in [256w,256w+256)
  const int ln = tid & 63;

  const float* wbase = Wt + (size_t)(ks * 32) * HID_ + j0 + q * 4;
  const float* hsbase = hs + ks * 32 + (ks >> 1) * 4;

  // preload loop-invariant W slice: rows ks*32..+31, cols q*4..+3
  float4 w[32];
#pragma unroll
  for (int kk = 0; kk < 32; ++kk)
    w[kk] = *(const float4*)(wbase + (size_t)kk * HID_);

  for (int t = 0; t < T_; ++t) {
    // --- xp prefetch (wave 0 = reducer); plain load, row t untouched so far
    float4 xpv = make_float4(0.f, 0.f, 0.f, 0.f);
    float* xpaddr = nullptr;
    if (tid < 64) {
      xpaddr = &hall[((size_t)(b0 + (tid >> 3)) * T_ + t) * HID_ + j0 + (tid & 7) * 4];
      xpv = *(const float4*)xpaddr;
    }

    float4 acc[8];
#pragma unroll
    for (int bi = 0; bi < 8; ++bi) acc[bi] = make_float4(0.f, 0.f, 0.f, 0.f);

    if (t > 0) {
      // --- per-wave stage-poll of h(t-1): 4 c-groups x 8 b = 32 tagged u64
      const u64 wantTag = (u64)(unsigned)(t - 1);
      const u64* src = hx + (size_t)((t - 1) & 1) * (B_ * HID_);
      while (true) {
        bool ok = true;
#pragma unroll
        for (int c = 0; c < 4; ++c) {
          const int k = wv * 256 + c * 64 + ln;
          const int o = k + ((k >> 6) << 2);  // skew matches hsbase formula
          u64 v[8];
#pragma unroll
          for (int b = 0; b < 8; ++b)
            v[b] = __hip_atomic_load(src + (size_t)(b0 + b) * HID_ + k,
                                     __ATOMIC_RELAXED, __HIP_MEMORY_SCOPE_AGENT);
#pragma unroll
          for (int b = 0; b < 8; ++b) {
            union { unsigned u; float f; } cv; cv.u = (unsigned)v[b];
            hs[b * BROW + o] = cv.f;          // idempotent; rewritten on retry
            ok &= ((v[b] >> 32) == wantTag);
          }
        }
        if (__all(ok)) break;
      }
      // no barrier: this wave staged exactly the columns it computes with

      // --- compute: 8 groups of 4 k; per g: 4k x 4j x 8b = 128 FMA, W in VGPR
#pragma unroll
      for (int g = 0; g < 8; ++g) {
        const int kk = g * 4;
#pragma unroll
        for (int bi = 0; bi < 8; ++bi) {
          const float4 hv = *(const float4*)(hsbase + bi * BROW + kk);
          acc[bi].x += hv.x * w[kk].x + hv.y * w[kk + 1].x + hv.z * w[kk + 2].x + hv.w * w[kk + 3].x;
          acc[bi].y += hv.x * w[kk].y + hv.y * w[kk + 1].y + hv.z * w[kk + 2].y + hv.w * w[kk + 3].y;
          acc[bi].z += hv.x * w[kk].z + hv.y * w[kk + 1].z + hv.z * w[kk + 2].z + hv.w * w[kk + 3].z;
          acc[bi].w += hv.x * w[kk].w + hv.y * w[kk + 1].w + hv.z * w[kk + 2].w + hv.w * w[kk + 3].w;
        }
      }
    }

    // --- write partial sums to red[t&1]
    float* redb = red + (t & 1) * REDSZ;
#pragma unroll
    for (int bi = 0; bi < 8; ++bi)
      *(float4*)&redb[ks * RED_STRIDE + bi * 32 + q * 4] = acc[bi];
    __syncthreads();  // THE one barrier: red complete; waves 1-3 run ahead

    // --- wave 0: reduce, tanh, publish tagged hx + plain hall
    if (tid < 64) {
      const int off = (tid >> 3) * 32 + (tid & 7) * 4;
      float4 sum = make_float4(0.f, 0.f, 0.f, 0.f);
#pragma unroll
      for (int kss = 0; kss < 32; ++kss) {
        const float4 r = *(const float4*)&redb[kss * RED_STRIDE + off];
        sum.x += r.x; sum.y += r.y; sum.z += r.z; sum.w += r.w;
      }
      float pk[4];
      pk[0] = tanhf(sum.x + xpv.x);
      pk[1] = tanhf(sum.y + xpv.y);
      pk[2] = tanhf(sum.z + xpv.z);
      pk[3] = tanhf(sum.w + xpv.w);

      // tagged publish: fire-and-forget, no ack, no flag
      u64* dst = hx + (size_t)(t & 1) * (B_ * HID_)
                    + (size_t)(b0 + (tid >> 3)) * HID_ + j0 + (tid & 7) * 4;
      const u64 tg = ((u64)(unsigned)t) << 32;
#pragma unroll
      for (int i = 0; i < 4; ++i) {
        union { float f; unsigned u; } cv; cv.f = pk[i];
        __hip_atomic_store(dst + i, tg | (u64)cv.u,
                           __ATOMIC_RELAXED, __HIP_MEMORY_SCOPE_AGENT);
      }
      // plain store for the final GEMM (kernel-end release flushes it)
      float4 o; o.x = pk[0]; o.y = pk[1]; o.z = pk[2]; o.w = pk[3];
      *(float4*)xpaddr = o;
    }
    // no trailing barrier: red WAR covered by parity + next step's barrier
  }
}

// ---------------------------------------------------------------------------
extern "C" void kernel_launch(void* const* d_in, const int* in_sizes, int n_in,
                              void* d_out, int out_size, void* d_ws, size_t ws_size,
                              hipStream_t stream) {
  (void)in_sizes; (void)n_in; (void)out_size; (void)ws_size;
  const float* input = (const float*)d_in[0];
  const float* W_ih  = (const float*)d_in[1];
  const float* W_hh  = (const float*)d_in[2];
  const float* bias  = (const float*)d_in[3];
  const float* W_out = (const float*)d_in[4];
  const float* b_out = (const float*)d_in[5];
  float* out = (float*)d_out;

  float* Wt   = (float*)d_ws;                  // 4 MiB
  float* hall = Wt + (size_t)HID_ * HID_;      // 128 MiB (x_proj, then h)
  // hx lives in the head of d_out: 2 x 64 x 1024 x 8 B = 1 MiB, memset to
  // 0xFF (tag 0xFFFFFFFF != any step), overwritten by the final GEMM.
  u64* hx = (u64*)d_out;

  hipMemsetAsync(hx, 0xFF, (size_t)2 * B_ * HID_ * sizeof(u64), stream);

  transpose_whh<<<dim3(32, 32), dim3(32, 8), 0, stream>>>(W_hh, Wt);

  gemm_bias<<<dim3(HID_ / 128, (B_ * T_) / 128), 256, 0, stream>>>(
      input, W_ih, bias, hall, B_ * T_, HID_, IN_);

  rnn_scan9<<<dim3(256), dim3(256), 0, stream>>>(Wt, hall, hx);

  gemm_bias<<<dim3(OUT_ / 128, (B_ * T_) / 128), 256, 0, stream>>>(
      hall, W_out, b_out, out, B_ * T_, OUT_, HID_);
}

// Round 7
// 3421.523 us; speedup vs baseline: 1.7819x; 1.2152x over previous
//
#include <hip/hip_runtime.h>

#define B_   64
#define T_   512
#define IN_  512
#define HID_ 1024
#define OUT_ 512

#define BROW 1092        // hs staging row stride (floats): 1024 data + skew pads
#define RED_STRIDE 260   // reduction slice stride (floats)
#define REDSZ (32 * RED_STRIDE)

typedef unsigned long long u64;

// ---------------------------------------------------------------------------
// K0: transpose W_hh [j][k] -> Wt [k][j] so scan W reads are lane-coalesced.
// ---------------------------------------------------------------------------
__global__ __launch_bounds__(256) void transpose_whh(const float* __restrict__ W,
                                                     float* __restrict__ Wt) {
  __shared__ float tile[32][33];
  const int bx = blockIdx.x * 32;  // k
  const int by = blockIdx.y * 32;  // j
  const int tx = threadIdx.x;
  const int ty = threadIdx.y;
#pragma unroll
  for (int i = 0; i < 32; i += 8)
    tile[ty + i][tx] = W[(size_t)(by + ty + i) * HID_ + bx + tx];
  __syncthreads();
#pragma unroll
  for (int i = 0; i < 32; i += 8)
    Wt[(size_t)(bx + ty + i) * HID_ + by + tx] = tile[tx][ty + i];
}

// ---------------------------------------------------------------------------
// K1/K3: C[M,N] = A[M,K] @ B[N,K]^T + bias[N].  fp32, 128x128 tile, BK=8.
// ---------------------------------------------------------------------------
__global__ __launch_bounds__(256) void gemm_bias(const float* __restrict__ A,
                                                 const float* __restrict__ Bm,
                                                 const float* __restrict__ bias,
                                                 float* __restrict__ C,
                                                 int M, int N, int K) {
  __shared__ float As[8][128];
  __shared__ float Bs[8][128];
  const int bm = blockIdx.y * 128;
  const int bn = blockIdx.x * 128;
  const int tid = threadIdx.x;
  const int tr = (tid / 16) * 8;
  const int tc = (tid % 16) * 8;
  const int lr = tid / 2;
  const int lk = (tid % 2) * 4;

  float acc[8][8];
#pragma unroll
  for (int i = 0; i < 8; i++)
#pragma unroll
    for (int j = 0; j < 8; j++) acc[i][j] = 0.f;

  for (int k0 = 0; k0 < K; k0 += 8) {
    float4 a = *(const float4*)&A[(size_t)(bm + lr) * K + k0 + lk];
    float4 b = *(const float4*)&Bm[(size_t)(bn + lr) * K + k0 + lk];
    As[lk + 0][lr] = a.x; As[lk + 1][lr] = a.y;
    As[lk + 2][lr] = a.z; As[lk + 3][lr] = a.w;
    Bs[lk + 0][lr] = b.x; Bs[lk + 1][lr] = b.y;
    Bs[lk + 2][lr] = b.z; Bs[lk + 3][lr] = b.w;
    __syncthreads();
#pragma unroll
    for (int k = 0; k < 8; k++) {
      float av[8], bv[8];
#pragma unroll
      for (int i = 0; i < 8; i++) av[i] = As[k][tr + i];
#pragma unroll
      for (int j = 0; j < 8; j++) bv[j] = Bs[k][tc + j];
#pragma unroll
      for (int i = 0; i < 8; i++)
#pragma unroll
        for (int j = 0; j < 8; j++) acc[i][j] += av[i] * bv[j];
    }
    __syncthreads();
  }

#pragma unroll
  for (int i = 0; i < 8; i++) {
#pragma unroll
    for (int j = 0; j < 8; j += 4) {
      float4 o;
      o.x = acc[i][j + 0] + bias[bn + tc + j + 0];
      o.y = acc[i][j + 1] + bias[bn + tc + j + 1];
      o.z = acc[i][j + 2] + bias[bn + tc + j + 2];
      o.w = acc[i][j + 3] + bias[bn + tc + j + 3];
      *(float4*)&C[(size_t)(bm + tr + i) * N + bn + tc + j] = o;
    }
  }
}

// ---------------------------------------------------------------------------
// K2: persistent scan, epoch-tagged data handoff (protocol as rnn_scan9).
// This round:
//  (1) W is FORCED into VGPRs: after the preload, an opaque asm "+v" on all
//      128 components prevents rematerialization, so the compiler must keep
//      the slice live (VGPR ~200, 1 block/CU: free).  scan9's VGPR=140
//      proved the compiler was re-loading W from L2 every step (~128 KB/
//      block/step) despite the source-level hoist.
//  (2) reduce/tanh/publish DISTRIBUTED across all 4 waves: each lane owns
//      one h[rb][rj] (rb=2*wv+(ln>>5), rj=ln&31): 32 scalar LDS reads
//      (2-way bank alias = free), 1 tanh, 1 tagged u64 publish, 1 hall
//      store.  Kills the wave-0 serial bottleneck.  kss summation order
//      unchanged (ascending) -> h bitwise identical.
// Deadlock-freedom: unchanged from scan9 (publish precedes the only wait;
// full-peer dependency bounds skew to < 2 steps, matching 2-deep parity).
// ---------------------------------------------------------------------------
__global__ __launch_bounds__(256, 1) void rnn_scan10(const float* __restrict__ Wt,
                                                     float* __restrict__ hall,
                                                     u64* __restrict__ hx) {
  __shared__ float hs[8 * BROW];   // staging, per-wave disjoint column ranges
  __shared__ float red[2 * REDSZ]; // ping-pong partial sums

  const int bid = blockIdx.x;
  const int jg = bid & 31;
  const int bg = bid >> 5;
  const int j0 = jg * 32;
  const int b0 = bg * 8;
  const int tid = threadIdx.x;
  const int q  = tid & 7;
  const int ks = tid >> 3;
  const int wv = tid >> 6;   // wave id 0..3; wave w stages k in [256w,256w+256)
  const int ln = tid & 63;

  // reduce/publish mapping: this lane owns h[rb][rj] of the block's 8x32 tile
  const int rb = 2 * wv + (ln >> 5);  // 0..7
  const int rj = ln & 31;             // 0..31

  const float* wbase = Wt + (size_t)(ks * 32) * HID_ + j0 + q * 4;
  const float* hsbase = hs + ks * 32 + (ks >> 1) * 4;

  // preload loop-invariant W slice: rows ks*32..+31, cols q*4..+3
  float4 w[32];
#pragma unroll
  for (int kk = 0; kk < 32; ++kk)
    w[kk] = *(const float4*)(wbase + (size_t)kk * HID_);
  // force residency: opaque asm makes each component an unknown asm output,
  // so the compiler cannot re-load it from memory inside the t-loop.
#pragma unroll
  for (int kk = 0; kk < 32; ++kk)
    __asm__ volatile("" : "+v"(w[kk].x), "+v"(w[kk].y), "+v"(w[kk].z), "+v"(w[kk].w));

  for (int t = 0; t < T_; ++t) {
    // --- per-lane xp load for this lane's reduce slot (fires before poll;
    //     latency hides under poll+compute).  hall row t is still x_proj.
    float* hrow = &hall[((size_t)(b0 + rb) * T_ + t) * HID_ + j0 + rj];
    const float xpv = *hrow;

    float4 acc[8];
#pragma unroll
    for (int bi = 0; bi < 8; ++bi) acc[bi] = make_float4(0.f, 0.f, 0.f, 0.f);

    if (t > 0) {
      // --- per-wave stage-poll of h(t-1): 4 c-groups x 8 b = 32 tagged u64
      const u64 wantTag = (u64)(unsigned)(t - 1);
      const u64* src = hx + (size_t)((t - 1) & 1) * (B_ * HID_);
      while (true) {
        bool ok = true;
#pragma unroll
        for (int c = 0; c < 4; ++c) {
          const int k = wv * 256 + c * 64 + ln;
          const int o = k + ((k >> 6) << 2);  // skew matches hsbase formula
          u64 v[8];
#pragma unroll
          for (int b = 0; b < 8; ++b)
            v[b] = __hip_atomic_load(src + (size_t)(b0 + b) * HID_ + k,
                                     __ATOMIC_RELAXED, __HIP_MEMORY_SCOPE_AGENT);
#pragma unroll
          for (int b = 0; b < 8; ++b) {
            union { unsigned u; float f; } cv; cv.u = (unsigned)v[b];
            hs[b * BROW + o] = cv.f;          // idempotent; rewritten on retry
            ok &= ((v[b] >> 32) == wantTag);
          }
        }
        if (__all(ok)) break;
      }
      __asm__ __volatile__("" ::: "memory");
      // no barrier: this wave staged exactly the columns it computes with

      // --- compute: 8 groups of 4 k; per g: 4k x 4j x 8b = 128 FMA, W in VGPR
#pragma unroll
      for (int g = 0; g < 8; ++g) {
        const int kk = g * 4;
#pragma unroll
        for (int bi = 0; bi < 8; ++bi) {
          const float4 hv = *(const float4*)(hsbase + bi * BROW + kk);
          acc[bi].x += hv.x * w[kk].x + hv.y * w[kk + 1].x + hv.z * w[kk + 2].x + hv.w * w[kk + 3].x;
          acc[bi].y += hv.x * w[kk].y + hv.y * w[kk + 1].y + hv.z * w[kk + 2].y + hv.w * w[kk + 3].y;
          acc[bi].z += hv.x * w[kk].z + hv.y * w[kk + 1].z + hv.z * w[kk + 2].z + hv.w * w[kk + 3].z;
          acc[bi].w += hv.x * w[kk].w + hv.y * w[kk + 1].w + hv.z * w[kk + 2].w + hv.w * w[kk + 3].w;
        }
      }
    }

    // --- write partial sums to red[t&1]
    float* redb = red + (t & 1) * REDSZ;
#pragma unroll
    for (int bi = 0; bi < 8; ++bi)
      *(float4*)&redb[ks * RED_STRIDE + bi * 32 + q * 4] = acc[bi];
    __syncthreads();  // THE one barrier: all partials in red before reduce

    // --- distributed reduce: every lane reduces its own h[rb][rj]
    {
      float sum = 0.f;
#pragma unroll
      for (int kss = 0; kss < 32; ++kss)
        sum += redb[kss * RED_STRIDE + rb * 32 + rj];
      const float h = tanhf(sum + xpv);

      // tagged publish: fire-and-forget, no ack, no flag
      union { float f; unsigned u; } cv; cv.f = h;
      u64* dst = hx + (size_t)(t & 1) * (B_ * HID_)
                    + (size_t)(b0 + rb) * HID_ + j0 + rj;
      __hip_atomic_store(dst, (((u64)(unsigned)t) << 32) | (u64)cv.u,
                         __ATOMIC_RELAXED, __HIP_MEMORY_SCOPE_AGENT);
      // plain store for the final GEMM (kernel-end release flushes it)
      *hrow = h;
    }
    // no trailing barrier: red WAR covered by parity + next step's barrier
  }
}

// ---------------------------------------------------------------------------
extern "C" void kernel_launch(void* const* d_in, const int* in_sizes, int n_in,
                              void* d_out, int out_size, void* d_ws, size_t ws_size,
                              hipStream_t stream) {
  (void)in_sizes; (void)n_in; (void)out_size; (void)ws_size;
  const float* input = (const float*)d_in[0];
  const float* W_ih  = (const float*)d_in[1];
  const float* W_hh  = (const float*)d_in[2];
  const float* bias  = (const float*)d_in[3];
  const float* W_out = (const float*)d_in[4];
  const float* b_out = (const float*)d_in[5];
  float* out = (float*)d_out;

  float* Wt   = (float*)d_ws;                  // 4 MiB
  float* hall = Wt + (size_t)HID_ * HID_;      // 128 MiB (x_proj, then h)
  // hx lives in the head of d_out: 2 x 64 x 1024 x 8 B = 1 MiB, memset to
  // 0xFF (tag 0xFFFFFFFF != any step), overwritten by the final GEMM.
  u64* hx = (u64*)d_out;

  hipMemsetAsync(hx, 0xFF, (size_t)2 * B_ * HID_ * sizeof(u64), stream);

  transpose_whh<<<dim3(32, 32), dim3(32, 8), 0, stream>>>(W_hh, Wt);

  gemm_bias<<<dim3(HID_ / 128, (B_ * T_) / 128), 256, 0, stream>>>(
      input, W_ih, bias, hall, B_ * T_, HID_, IN_);

  rnn_scan10<<<dim3(256), dim3(256), 0, stream>>>(Wt, hall, hx);

  gemm_bias<<<dim3(OUT_ / 128, (B_ * T_) / 128), 256, 0, stream>>>(
      hall, W_out, b_out, out, B_ * T_, OUT_, HID_);
}